// Round 8
// baseline (55.350 us; speedup 1.0000x reference)
//
#include <hip/hip_runtime.h>
#include <hip/hip_bf16.h>
#include <math.h>

#define BB 8
#define NN 2048
#define CC 128
#define DD 128

typedef __attribute__((ext_vector_type(8))) short short8;
typedef __attribute__((ext_vector_type(4))) float f32x4;

static __device__ __forceinline__ unsigned short f2bf(float f) {
    __hip_bfloat16 h = __float2bfloat16(f);
    return *reinterpret_cast<unsigned short*>(&h);
}
static __device__ __forceinline__ float bf2f(unsigned short u) {
    __hip_bfloat16 h = *reinterpret_cast<__hip_bfloat16*>(&u);
    return __bfloat162float(h);
}

// ---------------- Kernel P: pack adj bitmask + split W hi/lo
#define PACK_BLOCKS (NN * NN / 256)          // 16384
#define WSPL_BLOCKS (DD * CC / 256)          // 64
__global__ __launch_bounds__(256) void prep_kernel(
    const int* __restrict__ adj, unsigned int* __restrict__ padj,
    const float* __restrict__ W,
    unsigned short* __restrict__ Whi, unsigned short* __restrict__ Wlo)
{
    const int bx  = blockIdx.x;
    const int tid = threadIdx.x;
    if (bx < PACK_BLOCKS) {
        const int idx  = bx * 256 + tid;
        const int i    = idx >> 11;
        const int j    = idx & 2047;
        const int lane = tid & 63;
        int ad = adj[(size_t)i * NN + j];
        unsigned long long m = __ballot(ad > 0);
        if (lane == 0)  padj[i * 64 + (j >> 5)] = (unsigned int)m;
        if (lane == 32) padj[i * 64 + (j >> 5)] = (unsigned int)(m >> 32);
    } else {
        const int g = (bx - PACK_BLOCKS) * 256 + tid;
        float w = W[g];
        unsigned short h = f2bf(w);
        Whi[g] = h;
        Wlo[g] = f2bf(w - bf2f(h));
    }
}

// ---------------- Kernel A: Wh = x @ W^T via compensated MFMA.
// Writes WhbT bf16 [b][d][n], f1 (raw), EGp = pack(bf16 exp(f2), bf16 exp(0.2 f2)).
__global__ __launch_bounds__(256) void wh_kernel(
    const float* __restrict__ x,
    const unsigned short* __restrict__ Whi, const unsigned short* __restrict__ Wlo,
    const float* __restrict__ a,
    unsigned short* __restrict__ WhbT,
    float* __restrict__ f1, unsigned int* __restrict__ EGp)
{
    const int tid  = threadIdx.x;
    const int b    = blockIdx.y;
    const int n0   = blockIdx.x * 64;
    const int w    = tid >> 6;
    const int lane = tid & 63;
    const int fr   = lane & 15, fk = lane >> 4;
    const int n    = n0 + w * 16 + fr;

    short8 bh[4], bl[4];
    const float* xrow = &x[((size_t)(b * NN) + n) * CC];
    #pragma unroll
    for (int ks = 0; ks < 4; ++ks) {
        float xv[8];
        *(float4*)&xv[0] = *(const float4*)&xrow[(ks * 4 + fk) * 8];
        *(float4*)&xv[4] = *(const float4*)&xrow[(ks * 4 + fk) * 8 + 4];
        #pragma unroll
        for (int e = 0; e < 8; ++e) {
            unsigned short h = f2bf(xv[e]);
            bh[ks][e] = (short)h;
            bl[ks][e] = (short)f2bf(xv[e] - bf2f(h));
        }
    }

    f32x4 acc[8];
    #pragma unroll
    for (int dt = 0; dt < 8; ++dt) acc[dt] = (f32x4){0.f, 0.f, 0.f, 0.f};

    #pragma unroll
    for (int dt = 0; dt < 8; ++dt) {
        #pragma unroll
        for (int ks = 0; ks < 4; ++ks) {
            const int off = (dt * 16 + fr) * CC + (ks * 4 + fk) * 8;
            short8 aH = *(const short8*)&Whi[off];
            short8 aL = *(const short8*)&Wlo[off];
            acc[dt] = __builtin_amdgcn_mfma_f32_16x16x32_bf16(aH, bh[ks], acc[dt], 0, 0, 0);
            acc[dt] = __builtin_amdgcn_mfma_f32_16x16x32_bf16(aH, bl[ks], acc[dt], 0, 0, 0);
            acc[dt] = __builtin_amdgcn_mfma_f32_16x16x32_bf16(aL, bh[ks], acc[dt], 0, 0, 0);
        }
    }

    float p1 = 0.f, p2 = 0.f;
    #pragma unroll
    for (int dt = 0; dt < 8; ++dt) {
        #pragma unroll
        for (int r = 0; r < 4; ++r) {
            const int d = dt * 16 + fk * 4 + r;
            p1 += acc[dt][r] * a[d];
            p2 += acc[dt][r] * a[DD + d];
        }
    }
    p1 += __shfl_xor(p1, 16); p1 += __shfl_xor(p1, 32);
    p2 += __shfl_xor(p2, 16); p2 += __shfl_xor(p2, 32);
    if (fk == 0) {
        f1[b * NN + n] = p1;
        unsigned short e2 = f2bf(__expf(p2));
        unsigned short g2 = f2bf(__expf(0.2f * p2));
        EGp[b * NN + n] = (unsigned int)e2 | ((unsigned int)g2 << 16);
    }

    #pragma unroll
    for (int dt = 0; dt < 8; ++dt) {
        #pragma unroll
        for (int r = 0; r < 4; ++r) {
            const int d = dt * 16 + fk * 4 + r;
            WhbT[((size_t)(b * 128 + d)) * NN + n] = f2bf(acc[dt][r]);
        }
    }
}

// ---------------- Kernel C: MFMA attention, 64 i x 128 d per block, 4 waves,
// frag-linear LDS (conflict-free), 32-j chunks, double-buffered, 1 barrier/chunk.
template<int S, bool DIRECT>
__global__ __launch_bounds__(256, 4) void gat_kernel(
    const unsigned short* __restrict__ WhbT,   // [b][128 d][2048 n] bf16
    const unsigned int* __restrict__ padj,     // [2048][64] bitmask
    const float* __restrict__ f1,
    const unsigned int* __restrict__ EGp,      // packed bf16 (E2,G2)
    float* __restrict__ out,
    float* __restrict__ pPV, float* __restrict__ pS)
{
    constexpr int JS = NN / S;
    constexpr int NC = JS / 32;
    // frag-linear: tile t (16 rows x 32 k) occupies [t*512, t*512+512) ushorts;
    // lane l of the frag owns ushorts [t*512 + l*8, +8).
    __shared__ __align__(16) unsigned short PsL[2][64 * 32];   // 4 tiles/buf
    __shared__ __align__(16) unsigned short BsL[2][128 * 32];  // 8 tiles/buf
    __shared__ float Srow[64];
    __shared__ float Sred[64];

    const int tid   = threadIdx.x;
    const int i0    = blockIdx.x * 64;
    const int split = blockIdx.y;
    const int b     = blockIdx.z;
    const int jBeg  = split * JS;

    // P role: row = tid>>2 (64 rows), j-window = (tid&3)*8 within 32-j chunk
    const int prow = tid >> 2;
    const int jsub = tid & 3;
    const float f1r = f1[b * NN + i0 + prow];
    const float E1r = __expf(f1r);
    const float G1r = __expf(0.2f * f1r);
    const unsigned int* egBase = EGp + b * NN + jBeg + jsub * 8;
    const unsigned int* mkBase = padj + (size_t)(i0 + prow) * 64 + (jBeg >> 5);
    const int pslot = (prow >> 4) * 512 + (jsub * 16 + (prow & 15)) * 8;

    // B staging role: d-row = prow and prow+64
    const size_t wrow0 = (size_t)(b * 128 + prow) * NN + jBeg + jsub * 8;
    const size_t wrow1 = wrow0 + (size_t)64 * NN;
    const int bslot0 = pslot;          // same formula with d = prow
    const int bslot1 = pslot + 2048;   // tiles 4..7

    // MFMA role: wave (wr,wc) -> i-rows wr*32..+31, d-cols wc*64..+63
    const int w    = tid >> 6;
    const int wr   = w >> 1, wc = w & 1;
    const int lane = tid & 63;
    const int fr   = lane & 15, fk = lane >> 4;

    f32x4 acc[2][4];
    #pragma unroll
    for (int it = 0; it < 2; ++it)
        #pragma unroll
        for (int dt = 0; dt < 4; ++dt) acc[it][dt] = (f32x4){0.f, 0.f, 0.f, 0.f};

    float s_part = 0.f;
    unsigned int mkA, mkB;
    uint4 egA0, egA1, egB0, egB1, bsA0, bsA1, bsB0, bsB1;

#define LOADSET(mk, eg0, eg1, bs0, bs1, c) do {                              \
        mk  = mkBase[(c)];                                                   \
        eg0 = *(const uint4*)(egBase + (size_t)(c) * 32);                    \
        eg1 = *(const uint4*)(egBase + (size_t)(c) * 32 + 4);                \
        bs0 = *(const uint4*)&WhbT[wrow0 + (size_t)(c) * 32];                \
        bs1 = *(const uint4*)&WhbT[wrow1 + (size_t)(c) * 32];                \
    } while (0)

#define PSTORE(buf, mk, eg0, eg1, bs0, bs1) do {                             \
        unsigned int egw[8];                                                 \
        *(uint4*)&egw[0] = eg0; *(uint4*)&egw[4] = eg1;                      \
        unsigned int bits = ((mk) >> (jsub * 8)) & 0xffu;                    \
        unsigned short pks[8];                                               \
        float ss = 0.f;                                                      \
        _Pragma("unroll")                                                    \
        for (int e = 0; e < 8; ++e) {                                        \
            float e2 = bf2f((unsigned short)(egw[e] & 0xffffu));             \
            float g2 = bf2f((unsigned short)(egw[e] >> 16));                 \
            float mv = E1r * e2, gv = G1r * g2;                              \
            float wv = fmaxf(mv, gv);                                        \
            wv = ((bits >> e) & 1u) ? wv : 0.f;                              \
            unsigned short bw = f2bf(wv);                                    \
            pks[e] = bw; ss += bf2f(bw);                                     \
        }                                                                    \
        s_part += ss;                                                        \
        uint4 pk;                                                            \
        pk.x = (unsigned int)pks[0] | ((unsigned int)pks[1] << 16);          \
        pk.y = (unsigned int)pks[2] | ((unsigned int)pks[3] << 16);          \
        pk.z = (unsigned int)pks[4] | ((unsigned int)pks[5] << 16);          \
        pk.w = (unsigned int)pks[6] | ((unsigned int)pks[7] << 16);          \
        *(uint4*)&PsL[buf][pslot]  = pk;                                     \
        *(uint4*)&BsL[buf][bslot0] = bs0;                                    \
        *(uint4*)&BsL[buf][bslot1] = bs1;                                    \
    } while (0)

#define MFMASTEP(buf) do {                                                   \
        short8 aF0 = *(const short8*)&PsL[buf][(2 * wr + 0) * 512 + lane * 8]; \
        short8 aF1 = *(const short8*)&PsL[buf][(2 * wr + 1) * 512 + lane * 8]; \
        _Pragma("unroll")                                                    \
        for (int dt = 0; dt < 4; ++dt) {                                     \
            short8 bF = *(const short8*)&BsL[buf][(wc * 4 + dt) * 512 + lane * 8]; \
            acc[0][dt] = __builtin_amdgcn_mfma_f32_16x16x32_bf16(aF0, bF, acc[0][dt], 0, 0, 0); \
            acc[1][dt] = __builtin_amdgcn_mfma_f32_16x16x32_bf16(aF1, bF, acc[1][dt], 0, 0, 0); \
        }                                                                    \
    } while (0)

    // prologue: chunk 0 -> buf0; prefetch chunk 1
    LOADSET(mkA, egA0, egA1, bsA0, bsA1, 0);
    PSTORE(0, mkA, egA0, egA1, bsA0, bsA1);
    LOADSET(mkB, egB0, egB1, bsB0, bsB1, 1);
    __syncthreads();

    #pragma unroll 1
    for (int cc = 0; cc < NC; cc += 2) {
        // even chunk cc: read buf0; write buf1 (chunk cc+1) concurrently
        MFMASTEP(0);
        PSTORE(1, mkB, egB0, egB1, bsB0, bsB1);
        if (cc + 2 < NC) LOADSET(mkA, egA0, egA1, bsA0, bsA1, cc + 2);
        __syncthreads();
        // odd chunk cc+1: read buf1; write buf0 (chunk cc+2) concurrently
        MFMASTEP(1);
        if (cc + 2 < NC) PSTORE(0, mkA, egA0, egA1, bsA0, bsA1);
        if (cc + 3 < NC) LOADSET(mkB, egB0, egB1, bsB0, bsB1, cc + 3);
        __syncthreads();
    }

#undef LOADSET
#undef PSTORE
#undef MFMASTEP

    // row-sum: 4 threads per row (jsub group)
    {
        float v = s_part;
        v += __shfl_xor(v, 1); v += __shfl_xor(v, 2);
        if (jsub == 0) Srow[prow] = v;
    }
    __syncthreads();
    if (tid < 64) {
        float st = Srow[tid];
        if (DIRECT) Sred[tid] = 1.0f / st;
        else        pS[(size_t)(b * S + split) * NN + i0 + tid] = st;
    }
    __syncthreads();

    #pragma unroll
    for (int it = 0; it < 2; ++it) {
        #pragma unroll
        for (int dt = 0; dt < 4; ++dt) {
            #pragma unroll
            for (int r = 0; r < 4; ++r) {
                const int i = wr * 32 + it * 16 + fk * 4 + r;
                const int d = wc * 64 + dt * 16 + fr;
                const float av = acc[it][dt][r];
                if (DIRECT) {
                    float hv = av * Sred[i];
                    hv = (hv > 0.f) ? hv : expm1f(hv);
                    out[((size_t)(b * NN) + i0 + i) * DD + d] = hv;
                } else {
                    pPV[((size_t)(b * S + split) * NN + i0 + i) * DD + d] = av;
                }
            }
        }
    }
}

// ---------------- Kernel D: combine splits, normalize, elu
template<int S>
__global__ __launch_bounds__(256) void reduce_kernel(
    const float* __restrict__ pPV, const float* __restrict__ pS,
    float* __restrict__ out)
{
    const int idx = blockIdx.x * 256 + threadIdx.x;
    const int bi = idx >> 5;
    const int d4 = (idx & 31) * 4;
    const int b  = bi >> 11;
    const int i  = bi & 2047;
    float4 sum = make_float4(0.f, 0.f, 0.f, 0.f);
    float ssum = 0.f;
    #pragma unroll
    for (int s = 0; s < S; ++s) {
        size_t base = (size_t)(b * S + s) * NN + i;
        float4 v = *(const float4*)&pPV[base * DD + d4];
        sum.x += v.x; sum.y += v.y; sum.z += v.z; sum.w += v.w;
        ssum  += pS[base];
    }
    float inv = 1.0f / ssum;
    float4 h;
    h.x = sum.x * inv; h.y = sum.y * inv; h.z = sum.z * inv; h.w = sum.w * inv;
    h.x = (h.x > 0.f) ? h.x : expm1f(h.x);
    h.y = (h.y > 0.f) ? h.y : expm1f(h.y);
    h.z = (h.z > 0.f) ? h.z : expm1f(h.z);
    h.w = (h.w > 0.f) ? h.w : expm1f(h.w);
    *(float4*)&out[(size_t)bi * DD + d4] = h;
}

extern "C" void kernel_launch(void* const* d_in, const int* in_sizes, int n_in,
                              void* d_out, int out_size, void* d_ws, size_t ws_size,
                              hipStream_t stream) {
    const float* x   = (const float*)d_in[0];
    const int*   adj = (const int*)d_in[1];
    const float* W   = (const float*)d_in[2];
    const float* a   = (const float*)d_in[3];
    float* out = (float*)d_out;

    char* p = (char*)d_ws;
    unsigned short* WhbT = (unsigned short*)p; p += (size_t)BB * NN * DD * 2;  // 4 MB
    float* f1 = (float*)p;          p += (size_t)BB * NN * 4;                  // 64 KB
    unsigned int* EGp = (unsigned int*)p; p += (size_t)BB * NN * 4;            // 64 KB
    unsigned short* Whi = (unsigned short*)p; p += (size_t)DD * CC * 2;        // 32 KB
    unsigned short* Wlo = (unsigned short*)p; p += (size_t)DD * CC * 2;        // 32 KB
    unsigned int* padj = (unsigned int*)p;    p += (size_t)NN * 64 * 4;        // 512 KB
    float* pPV = (float*)p;

    const size_t base_bytes = (size_t)(p - (char*)d_ws);
    const size_t per_split  = (size_t)BB * NN * DD * 4 + (size_t)BB * NN * 4;

    prep_kernel<<<PACK_BLOCKS + WSPL_BLOCKS, 256, 0, stream>>>(adj, padj, W, Whi, Wlo);
    wh_kernel<<<dim3(NN / 64, BB), 256, 0, stream>>>(x, Whi, Wlo, a, WhbT, f1, EGp);

    if (ws_size >= base_bytes + 4 * per_split) {
        constexpr int S = 4;
        float* pS = pPV + (size_t)S * BB * NN * DD;
        gat_kernel<S, false><<<dim3(NN / 64, S, BB), 256, 0, stream>>>(
            WhbT, padj, f1, EGp, out, pPV, pS);
        reduce_kernel<S><<<BB * NN * DD / 4 / 256, 256, 0, stream>>>(pPV, pS, out);
    } else if (ws_size >= base_bytes + 2 * per_split) {
        constexpr int S = 2;
        float* pS = pPV + (size_t)S * BB * NN * DD;
        gat_kernel<S, false><<<dim3(NN / 64, S, BB), 256, 0, stream>>>(
            WhbT, padj, f1, EGp, out, pPV, pS);
        reduce_kernel<S><<<BB * NN * DD / 4 / 256, 256, 0, stream>>>(pPV, pS, out);
    } else {
        gat_kernel<1, true><<<dim3(NN / 64, 1, BB), 256, 0, stream>>>(
            WhbT, padj, f1, EGp, out, nullptr, nullptr);
    }
}